// Round 8
// baseline (6943.559 us; speedup 1.0000x reference)
//
#include <hip/hip_runtime.h>

// ---------- types / helpers ----------
typedef __attribute__((ext_vector_type(8))) short bf16x8;   // 8 bf16 (4 VGPRs)
typedef __attribute__((ext_vector_type(4))) float f32x4;    // MFMA accumulator

#define GLOAD_LDS16(g, l)                                                     \
  __builtin_amdgcn_global_load_lds(                                           \
      (const __attribute__((address_space(1))) void*)(g),                     \
      (__attribute__((address_space(3))) void*)(l), 16, 0, 0)

#define ALOAD64(p)  __hip_atomic_load((p), __ATOMIC_RELAXED, __HIP_MEMORY_SCOPE_AGENT)
#define ALOADU32(p) __hip_atomic_load((p), __ATOMIC_RELAXED, __HIP_MEMORY_SCOPE_AGENT)
#define ASTOREU32(p, v) __hip_atomic_store((p), (v), __ATOMIC_RELAXED, __HIP_MEMORY_SCOPE_AGENT)

#define TMASK 0xFFFF0000FFFF0000ull   // tag halves of a u64 (2 tagged u32)

__device__ __forceinline__ unsigned short f2b(float f) {
  union { float f; unsigned int i; } v; v.f = f;
  unsigned int u = v.i;
  u += 0x7fffu + ((u >> 16) & 1u);   // RNE
  return (unsigned short)(u >> 16);
}
__device__ __forceinline__ float sigm(float x) { return 1.f / (1.f + expf(-x)); }

// Problem constants
#define HH   1024
#define H3   3072
#define BB   8
#define SP   384     // padded sequence (383 real + 1 pad)
#define SL   383
#define VV   32000
#define II   512
#define MQ   2048    // B*T rows for attention tail

// TAG(step) = step+1: never 0 (rings are zeroed in-graph each replay).
#define TAG(s) ((unsigned)((s) + 1))

// ---------- fp32 -> bf16 bulk convert ----------
__global__ void k_f32_to_bf16(const float* __restrict__ src,
                              unsigned short* __restrict__ dst, int n4) {
  int i = blockIdx.x * 256 + threadIdx.x;
  if (i >= n4) return;
  float4 v = ((const float4*)src)[i];
  ushort4 o;
  o.x = f2b(v.x); o.y = f2b(v.y); o.z = f2b(v.z); o.w = f2b(v.w);
  ((ushort4*)dst)[i] = o;
}

// ---------- zero u32 ----------
__global__ void k_zero_u32(unsigned int* p, int n) {
  int i = blockIdx.x * 256 + threadIdx.x;
  if (i < n) p[i] = 0u;
}

// ---------- embedding gather -> bf16, layout m = b*384 + s ----------
__global__ void k_embed(const int* __restrict__ input, const int* __restrict__ targets,
                        const float* __restrict__ embed_w, unsigned short* __restrict__ emb) {
  int m = blockIdx.x;              // 0..3071
  int b = m / SP, s = m % SP;
  unsigned short* dst = emb + (size_t)m * II;
  if (s == SL) {                   // pad row
    for (int i = threadIdx.x; i < II; i += 256) dst[i] = 0;
    return;
  }
  int tok = (s < 128) ? input[b * 128 + s] : targets[b * 256 + (s - 128)];
  const float* srcw = embed_w + (size_t)tok * II;
  for (int i = threadIdx.x; i < II; i += 256) dst[i] = f2b(srcw[i]);
}

// ---------- 2-phase double-buffered bf16 GEMM: C = A@W^T + bias ----------
template<bool TANH, bool OUTBF16>
__global__ __launch_bounds__(256) void k_gemm_bt(
    const unsigned short* __restrict__ A, const unsigned short* __restrict__ W,
    const float* __restrict__ bias, void* __restrict__ Cout,
    int M, int N, int K) {
  __shared__ __align__(16) unsigned short As[2][128 * 32];
  __shared__ __align__(16) unsigned short Ws[2][128 * 32];
  const int tid = threadIdx.x;
  const int gx = gridDim.x;
  const int nwg = gx * gridDim.y;
  int orig = blockIdx.y * gx + blockIdx.x;
  int wg = ((nwg & 7) == 0) ? ((orig & 7) * (nwg >> 3) + (orig >> 3)) : orig;
  const int mBase = (wg / gx) * 128, nBase = (wg % gx) * 128;
  const int wid = tid >> 6, lane = tid & 63;
  const int wr = wid >> 1, wc = wid & 1;
  f32x4 acc[4][4];
#pragma unroll
  for (int i = 0; i < 4; ++i)
#pragma unroll
    for (int j = 0; j < 4; ++j) acc[i][j] = (f32x4){0.f, 0.f, 0.f, 0.f};

  const int r0 = tid >> 2, c0 = (tid & 3) * 8;   // staging chunk (8 bf16 = 16B)
  const int kq8 = (lane >> 4) * 8;

  auto stage = [&](int kt, int b) {
#pragma unroll
    for (int pass = 0; pass < 2; ++pass) {
      int r = pass * 64 + r0;
      GLOAD_LDS16(A + (size_t)(mBase + r) * K + kt + c0, &As[b][r * 32 + c0]);
      GLOAD_LDS16(W + (size_t)(nBase + r) * K + kt + c0, &Ws[b][r * 32 + c0]);
    }
  };

  stage(0, 0);
  int cur = 0;
  for (int kt = 0; kt < K; kt += 32) {
    asm volatile("s_waitcnt vmcnt(0)" ::: "memory");   // buf[cur] landed
    __syncthreads();
    if (kt + 32 < K) stage(kt + 32, cur ^ 1);          // overlaps with MFMA below
    bf16x8 af[4], bfr[4];
#pragma unroll
    for (int mf = 0; mf < 4; ++mf)
      af[mf] = *(const bf16x8*)&As[cur][(wr * 64 + mf * 16 + (lane & 15)) * 32 + kq8];
#pragma unroll
    for (int nf = 0; nf < 4; ++nf)
      bfr[nf] = *(const bf16x8*)&Ws[cur][(wc * 64 + nf * 16 + (lane & 15)) * 32 + kq8];
#pragma unroll
    for (int mf = 0; mf < 4; ++mf)
#pragma unroll
      for (int nf = 0; nf < 4; ++nf)
        acc[mf][nf] = __builtin_amdgcn_mfma_f32_16x16x32_bf16(af[mf], bfr[nf], acc[mf][nf], 0, 0, 0);
    cur ^= 1;
  }
  const int rq = (lane >> 4) * 4;
#pragma unroll
  for (int mf = 0; mf < 4; ++mf) {
#pragma unroll
    for (int nf = 0; nf < 4; ++nf) {
      int n = nBase + wc * 64 + nf * 16 + (lane & 15);
      float bvv = bias[n];
#pragma unroll
      for (int i = 0; i < 4; ++i) {
        int m = mBase + wr * 64 + mf * 16 + rq + i;
        float v = acc[mf][nf][i] + bvv;
        if (TANH) v = tanhf(v);
        if (OUTBF16) ((unsigned short*)Cout)[(size_t)m * N + n] = f2b(v);
        else         ((float*)Cout)[(size_t)m * N + n] = v;
      }
    }
  }
}

// ---------- persistent cooperative GRU recurrence, tagged-data (fixed poll) ----------
// grid = 192 WGs x 256 thr. WG g<64: layer0 (16 cols). g>=64: layer1 (8 cols).
// h rings: 8 slots x 8 batch x 1024 cols of u32 = (TAG(step)<<16)|bf16.
// PRODUCERS ARE FIRE-AND-FORGET (no drain/flag; tag+value share one word =
// race-free by construction; agent atomics are L3-coherent cross-XCD).
// CONSUMER poll (the round-6 fix): canary-first (1 u64 per producer-WG
// overlapping the thread's slice), then one sweep keeping successes in regs,
// re-loading ONLY stale words (pend bitmask) -> traffic ~ payload x (1+eps).
// WAR: own-word rflag[slot][wg]=TAG(s) posted after stage barrier; wave 1
// checks rflag[s-4] full every 4 steps (4-step slack; never blocks).
__global__ __launch_bounds__(256) void k_recur(
    const unsigned short* __restrict__ whh0, const unsigned short* __restrict__ wih1,
    const unsigned short* __restrict__ whh1,
    const float* __restrict__ gi0,
    const float* __restrict__ bhh0, const float* __restrict__ bih1,
    const float* __restrict__ bhh1,
    unsigned* __restrict__ h1g, unsigned* __restrict__ h2g,
    float* __restrict__ Obuf, unsigned* cnt) {
  extern __shared__ unsigned char smem[];
  unsigned short* wlds  = (unsigned short*)smem;              // 48x1024 bf16 = 98304B
  unsigned short* hA    = (unsigned short*)(smem + 98304);    // 8x1024 bf16 = 16384B
  unsigned short* hB    = (unsigned short*)(smem + 114688);   // 16384B
  unsigned short* zrow  = (unsigned short*)(smem + 131072);   // 1024 bf16 zeros
  float*          gacc  = (float*)(smem + 133120);            // 4*16*16 f32 = 4096B

  unsigned* rflag = cnt;            // [8][192]

  const int g = blockIdx.x, tid = threadIdx.x;
  const int layer = (g >= 64) ? 1 : 0;
  const int j0 = layer ? (g - 64) * 8 : g * 16;

  // ---- one-time: weight rows into LDS (XOR-swizzled source, linear dest) ----
  for (int p = 0; p < 24; ++p) {
    int c = p * 256 + tid;          // 16B chunks
    int rr = c >> 7;                // LDS row 0..47
    int co = (c & 127) * 8;
    int cs = co ^ ((rr & 7) * 8);
    const unsigned short* src;
    if (layer == 0) {
      int grow = (rr >> 4) * 1024 + j0 + (rr & 15);
      src = whh0 + (size_t)grow * 1024 + cs;
    } else {
      const unsigned short* base; int grow;
      if (rr < 16)      { base = wih1; grow = (rr < 8) ? (j0 + rr) : (1024 + j0 + rr - 8); }
      else if (rr < 32) { base = whh1; int r2 = rr - 16; grow = (r2 < 8) ? (j0 + r2) : (1024 + j0 + r2 - 8); }
      else if (rr < 40) { base = wih1; grow = 2048 + j0 + (rr - 32); }
      else              { base = whh1; grow = 2048 + j0 + (rr - 40); }
      src = base + (size_t)grow * 1024 + cs;
    }
    GLOAD_LDS16(src, wlds + (size_t)rr * 1024 + co);
  }
  { // zero pad row + gacc (zeros feed gates on steps before MFMA starts)
    ((unsigned int*)zrow)[tid]       = 0u;
    ((unsigned int*)zrow)[tid + 256] = 0u;
    for (int i = tid; i < 1024; i += 256) gacc[i] = 0.f;
  }
  __syncthreads();

  const int w = tid >> 6, lane = tid & 63;
  const int arow = lane & 15, kq8 = (lane >> 4) * 8, bb = lane & 15;

  // hoisted gate constants + running state
  float c0r = 0.f, c0z = 0.f, c0n = 0.f;
  float c1ir = 0.f, c1iz = 0.f, c1in = 0.f, c1hr = 0.f, c1hz = 0.f, c1hn = 0.f;
  float hprev = 0.f;
  if (layer == 0) {
    if (tid < 128) { int j = j0 + (tid >> 3); c0r = bhh0[j]; c0z = bhh0[1024 + j]; c0n = bhh0[2048 + j]; }
  } else {
    if (tid < 64)  { int j = j0 + (tid >> 3);
      c1ir = bih1[j]; c1iz = bih1[1024 + j]; c1in = bih1[2048 + j];
      c1hr = bhh1[j]; c1hz = bhh1[1024 + j]; c1hn = bhh1[2048 + j]; }
  }

  // MFMA config (constant per thread)
  bool wact; int tb, nrows; int hsel;
  if (layer == 0) { wact = (w < 3); tb = w * 16; nrows = 16; hsel = 0; }
  else { wact = true; tb = (w < 2) ? w * 16 : (32 + (w - 2) * 8); nrows = (w < 2) ? 16 : 8;
         hsel = (w & 1); }
  const unsigned short* abase; int ax;
  if (arow < nrows) { abase = wlds + (size_t)(tb + arow) * 1024; ax = (arow & 7) * 8; }
  else              { abase = zrow; ax = 0; }
  const unsigned short* bbase0; int bx;
  {
    const unsigned short* hX = hsel ? hB : hA;
    if (bb < 8) { bbase0 = hX + (size_t)bb * 1024; bx = (bb & 7) * 8; }
    else        { bbase0 = zrow; bx = 0; }
  }
  const int rq = (lane >> 4) * 4;

  // staging geometry: each thread owns row tid&7, 32-elem col chunk
  const int srow = tid & 7;
  const int sc0  = (tid >> 3) * 32;
  const int sx   = srow * 8;

  for (int s = 0; s < 384; ++s) {
    const bool act = layer ? (s >= 1) : (s <= 382);
    const unsigned* h1rs = h1g + ((s - 1) & 7) * 8192;
    const unsigned* h2rs = h2g + ((s - 2) & 7) * 8192;
    unsigned* h1ws = h1g + (s & 7) * 8192;
    unsigned* h2ws = h2g + ((s - 1) & 7) * 8192;

    // 0) gi0 prefetch (L0; normal cached loads; in flight during the poll)
    float pr = 0.f, pz = 0.f, pn = 0.f;
    if (layer == 0 && act && tid < 128) {
      int cc = tid >> 3, b = tid & 7; int j = j0 + cc;
      size_t m3 = ((size_t)b * SP + s) * H3;
      pr = gi0[m3 + j]; pz = gi0[m3 + 1024 + j]; pn = gi0[m3 + 2048 + j];
    }

    // WAR check (wave 1, every 4 steps, 4-stale; normally instant)
    if (w == 1 && (s & 3) == 0 && s >= 4) {
      const unsigned t = TAG(s - 4);
      unsigned* rf = rflag + ((s - 4) & 7) * 192;
      for (int it = 0; it < 100000; ++it) {
        int ok = (ALOADU32(rf + lane) == t)
               & (ALOADU32(rf + 64 + lane) == t)
               & (ALOADU32(rf + 128 + lane) == t);
        if (__all(ok)) break;                 // bounded: loud fail, not a hang
        __builtin_amdgcn_s_sleep(1);
      }
    }

    // 1) tag-poll stage: canary-first, then sweep with retry-failures-only
    if (act && s >= 1) {
      const bool use2 = (layer == 1) && (s >= 2);
      const unsigned long long* p1 = (const unsigned long long*)(h1rs + srow * 1024 + sc0);
      const unsigned long long* p2 = (const unsigned long long*)(h2rs + srow * 1024 + sc0);
      unsigned t1 = TAG(s - 1), t2 = TAG(s - 2);
      unsigned long long pat1 = ((unsigned long long)t1 << 16) | ((unsigned long long)t1 << 48);
      unsigned long long pat2 = ((unsigned long long)t2 << 16) | ((unsigned long long)t2 << 48);
      unsigned long long v1[16], v2[16];
      // canary: one u64 per producer-WG overlapping this slice
      for (int it = 0; it < 200000; ++it) {
        v1[0] = ALOAD64(p1 + 0); v1[8] = ALOAD64(p1 + 8);
        unsigned long long d = (v1[0] ^ pat1) | (v1[8] ^ pat1);
        if (use2) {
          v2[0] = ALOAD64(p2 + 0); v2[4] = ALOAD64(p2 + 4);
          v2[8] = ALOAD64(p2 + 8); v2[12] = ALOAD64(p2 + 12);
          d |= (v2[0] ^ pat2) | (v2[4] ^ pat2) | (v2[8] ^ pat2) | (v2[12] ^ pat2);
        }
        if (!(d & TMASK)) break;
        __builtin_amdgcn_s_sleep(1);
      }
      // sweep + retry only stale words
      unsigned pend1 = 0xfefeu;                       // canaries 0,8 done
      unsigned pend2 = use2 ? 0xeeeeu : 0u;           // canaries 0,4,8,12 done
      for (int it = 0; it < 200000; ++it) {
#pragma unroll
        for (int i = 0; i < 16; ++i) if (pend1 & (1u << i)) {
          v1[i] = ALOAD64(p1 + i);
          if (!((v1[i] ^ pat1) & TMASK)) pend1 &= ~(1u << i);
        }
        if (use2) {
#pragma unroll
          for (int i = 0; i < 16; ++i) if (pend2 & (1u << i)) {
            v2[i] = ALOAD64(p2 + i);
            if (!((v2[i] ^ pat2) & TMASK)) pend2 &= ~(1u << i);
          }
        }
        if (!(pend1 | pend2)) break;
        __builtin_amdgcn_s_sleep(1);
      }
      // unpack to bf16 + XOR-swizzled LDS write
      unsigned short* lr1 = hA + srow * 1024;
#pragma unroll
      for (int gb = 0; gb < 4; ++gb) {
        uint4 q;
        q.x = (unsigned)(v1[gb*4+0] & 0xffffu) | ((unsigned)(v1[gb*4+0] >> 16) & 0xffff0000u);
        q.y = (unsigned)(v1[gb*4+1] & 0xffffu) | ((unsigned)(v1[gb*4+1] >> 16) & 0xffff0000u);
        q.z = (unsigned)(v1[gb*4+2] & 0xffffu) | ((unsigned)(v1[gb*4+2] >> 16) & 0xffff0000u);
        q.w = (unsigned)(v1[gb*4+3] & 0xffffu) | ((unsigned)(v1[gb*4+3] >> 16) & 0xffff0000u);
        *(uint4*)(lr1 + ((sc0 + 8 * gb) ^ sx)) = q;
      }
      if (use2) {
        unsigned short* lr2 = hB + srow * 1024;
#pragma unroll
        for (int gb = 0; gb < 4; ++gb) {
          uint4 q;
          q.x = (unsigned)(v2[gb*4+0] & 0xffffu) | ((unsigned)(v2[gb*4+0] >> 16) & 0xffff0000u);
          q.y = (unsigned)(v2[gb*4+1] & 0xffffu) | ((unsigned)(v2[gb*4+1] >> 16) & 0xffff0000u);
          q.z = (unsigned)(v2[gb*4+2] & 0xffffu) | ((unsigned)(v2[gb*4+2] >> 16) & 0xffff0000u);
          q.w = (unsigned)(v2[gb*4+3] & 0xffffu) | ((unsigned)(v2[gb*4+3] >> 16) & 0xffff0000u);
          *(uint4*)(lr2 + ((sc0 + 8 * gb) ^ sx)) = q;
        }
      }
    }
    __syncthreads();                 // stage complete (slot reads done)

    // reads done for this step -> post own-word rflag (fire-and-forget)
    if (tid == 1) ASTOREU32(rflag + (s & 7) * 192 + g, TAG(s));

    // 2) MFMA (skip waves whose h operand doesn't exist yet)
    bool domfma = act && wact && (layer == 0 ? (s >= 1) : (hsel == 0 ? (s >= 1) : (s >= 2)));
    if (domfma) {
      f32x4 a0 = (f32x4){0.f, 0.f, 0.f, 0.f};
      f32x4 a1 = (f32x4){0.f, 0.f, 0.f, 0.f};
#pragma unroll
      for (int kt = 0; kt < 32; kt += 2) {
        int ko0 = kt * 32 + kq8, ko1 = ko0 + 32;
        bf16x8 av0 = *(const bf16x8*)(abase + (ko0 ^ ax));
        bf16x8 hv0 = *(const bf16x8*)(bbase0 + (ko0 ^ bx));
        bf16x8 av1 = *(const bf16x8*)(abase + (ko1 ^ ax));
        bf16x8 hv1 = *(const bf16x8*)(bbase0 + (ko1 ^ bx));
        a0 = __builtin_amdgcn_mfma_f32_16x16x32_bf16(av0, hv0, a0, 0, 0, 0);
        a1 = __builtin_amdgcn_mfma_f32_16x16x32_bf16(av1, hv1, a1, 0, 0, 0);
      }
#pragma unroll
      for (int i = 0; i < 4; ++i)
        gacc[w * 256 + (rq + i) * 16 + (lane & 15)] = a0[i] + a1[i];
    }
    __syncthreads();

    // 3) gates (fp32) + tagged fire-and-forget h stores + Obuf
    if (act) {
      if (layer == 0 && tid < 128) {
        int cc = tid >> 3, b = tid & 7; int j = j0 + cc;
        float gr = pr + gacc[cc * 16 + b]       + c0r;
        float gz = pz + gacc[256 + cc * 16 + b] + c0z;
        float hg =      gacc[512 + cc * 16 + b] + c0n;
        float r = sigm(gr), z = sigm(gz);
        float n = tanhf(pn + r * hg);
        float hn = (1.f - z) * n + z * hprev;
        hprev = hn;
        unsigned val = (TAG(s) << 16) | (unsigned)f2b(hn);
        ASTOREU32(h1ws + b * 1024 + j, val);
      } else if (layer == 1 && tid < 64) {
        int cc = tid >> 3, b = tid & 7; int j = j0 + cc;
        float gr = gacc[cc * 16 + b]       + c1ir + gacc[256 + cc * 16 + b]       + c1hr;
        float gz = gacc[(8 + cc) * 16 + b] + c1iz + gacc[256 + (8 + cc) * 16 + b] + c1hz;
        float gn = gacc[512 + cc * 16 + b] + c1in;
        float hg = gacc[768 + cc * 16 + b] + c1hn;
        float r = sigm(gr), z = sigm(gz);
        float n = tanhf(gn + r * hg);
        float hn = (1.f - z) * n + z * hprev;
        hprev = hn;
        unsigned val = (TAG(s - 1) << 16) | (unsigned)f2b(hn);
        ASTOREU32(h2ws + b * 1024 + j, val);
        Obuf[((size_t)b * SP + (s - 1)) * 1024 + j] = hn;   // normal store; flushed at kernel end
      }
    }
    // fire-and-forget: no end-of-step drain/barrier/flag
  }
}

// ---------- fused masked attention (fp32), writes X = [Q | ctx] as bf16 ----------
__global__ __launch_bounds__(256) void k_attn(const float* __restrict__ O,
                                              unsigned short* __restrict__ X) {
  __shared__ float sc[16][384];
  __shared__ float red[16][16];
  __shared__ float rowstat[16];
  const int wg = blockIdx.x;
  const int b = wg >> 4, q0 = (wg & 15) * 16;
  const int tid = threadIdx.x;
  const int qi = tid >> 4, kk = tid & 15;
  const int q = q0 + qi;                       // 0..255
  const float* Ob = O + (size_t)b * SP * 1024;
  const float* Qrow = Ob + (size_t)(127 + q) * 1024;

  for (int kb = 0; kb < 24; ++kb) {
    int k = kb * 16 + kk;
    float v = -INFINITY;
    if (k < 127 + q) {
      const float* Orow = Ob + (size_t)k * 1024;
      float a = 0.f;
      for (int h = 0; h < 1024; h += 4) {
        float4 qv = *(const float4*)(Qrow + h);
        float4 ov = *(const float4*)(Orow + h);
        a += qv.x * ov.x + qv.y * ov.y + qv.z * ov.z + qv.w * ov.w;
      }
      v = a;
    }
    sc[qi][k] = v;
  }
  __syncthreads();
  float mx = -INFINITY;
  for (int k = kk; k < 384; k += 16) mx = fmaxf(mx, sc[qi][k]);
  red[qi][kk] = mx;
  __syncthreads();
  if (kk == 0) {
    float m2 = -INFINITY;
    for (int i = 0; i < 16; ++i) m2 = fmaxf(m2, red[qi][i]);
    rowstat[qi] = m2;
  }
  __syncthreads();
  float rmax = rowstat[qi];
  float lsum = 0.f;
  for (int k = kk; k < 384; k += 16) {
    float v = sc[qi][k];
    float e = (v == -INFINITY) ? 0.f : expf(v - rmax);
    sc[qi][k] = e; lsum += e;
  }
  red[qi][kk] = lsum;
  __syncthreads();
  if (kk == 0) {
    float s2 = 0.f;
    for (int i = 0; i < 16; ++i) s2 += red[qi][i];
    rowstat[qi] = 1.f / s2;
  }
  __syncthreads();
  float rinv = rowstat[qi];

  const int hb = kk * 64;
  float4 acc[16];
#pragma unroll
  for (int i = 0; i < 16; ++i) acc[i] = (float4){0.f, 0.f, 0.f, 0.f};
  for (int k = 0; k < 127 + q; ++k) {
    float a = sc[qi][k];
    const float* Orow = Ob + (size_t)k * 1024 + hb;
#pragma unroll
    for (int i = 0; i < 16; ++i) {
      float4 ov = *(const float4*)(Orow + i * 4);
      acc[i].x += a * ov.x; acc[i].y += a * ov.y;
      acc[i].z += a * ov.z; acc[i].w += a * ov.w;
    }
  }
  unsigned short* Xrow = X + (size_t)(b * 256 + q) * 2048;
#pragma unroll
  for (int i = 0; i < 16; ++i) {
    int h = hb + i * 4;
    float4 qv = *(const float4*)(Qrow + h);
    Xrow[h + 0] = f2b(qv.x); Xrow[h + 1] = f2b(qv.y);
    Xrow[h + 2] = f2b(qv.z); Xrow[h + 3] = f2b(qv.w);
    Xrow[1024 + h + 0] = f2b(acc[i].x * rinv);
    Xrow[1024 + h + 1] = f2b(acc[i].y * rinv);
    Xrow[1024 + h + 2] = f2b(acc[i].z * rinv);
    Xrow[1024 + h + 3] = f2b(acc[i].w * rinv);
  }
}

// ---------- host ----------
extern "C" void kernel_launch(void* const* d_in, const int* in_sizes, int n_in,
                              void* d_out, int out_size, void* d_ws, size_t ws_size,
                              hipStream_t stream) {
  (void)in_sizes; (void)n_in; (void)out_size; (void)ws_size;
  const int*   input   = (const int*)d_in[0];
  const int*   targets = (const int*)d_in[1];
  const float* embed_w = (const float*)d_in[2];
  const float* Wih0 = (const float*)d_in[3];
  const float* Whh0 = (const float*)d_in[4];
  const float* bih0 = (const float*)d_in[5];
  const float* bhh0 = (const float*)d_in[6];
  const float* Wih1 = (const float*)d_in[7];
  const float* Whh1 = (const float*)d_in[8];
  const float* bih1 = (const float*)d_in[9];
  const float* bhh1 = (const float*)d_in[10];
  const float* Wc   = (const float*)d_in[11];
  const float* bc   = (const float*)d_in[12];
  const float* Wv   = (const float*)d_in[13];
  const float* bv   = (const float*)d_in[14];
  float* out = (float*)d_out;

  char* ws = (char*)d_ws;
  size_t off = 0;
  auto alloc = [&](size_t bytes) {
    void* p = ws + off; off += (bytes + 255) & ~(size_t)255; return p;
  };
  unsigned short* Wih0b = (unsigned short*)alloc((size_t)H3 * II * 2);
  unsigned short* Whh0b = (unsigned short*)alloc((size_t)H3 * HH * 2);
  unsigned short* Wih1b = (unsigned short*)alloc((size_t)H3 * HH * 2);
  unsigned short* Whh1b = (unsigned short*)alloc((size_t)H3 * HH * 2);
  unsigned short* Wcb   = (unsigned short*)alloc((size_t)HH * 2048 * 2);
  unsigned short* Wvb   = (unsigned short*)alloc((size_t)VV * HH * 2);
  unsigned short* EMBb  = (unsigned short*)alloc((size_t)BB * SP * II * 2);
  float*          GI0   = (float*)alloc((size_t)BB * SP * H3 * 4);
  unsigned*       H1G   = (unsigned*)alloc(8 * 8192 * 4);    // 256KB tagged ring
  unsigned*       H2G   = (unsigned*)alloc(8 * 8192 * 4);    // 256KB tagged ring (contiguous)
  unsigned*       CNT   = (unsigned*)alloc(1536 * 4);        // rflag, contiguous after H2G
  float*          OBUF  = (float*)alloc((size_t)BB * SP * HH * 4);
  unsigned short* Xb    = (unsigned short*)alloc((size_t)MQ * 2048 * 2);
  unsigned short* COMBb = (unsigned short*)alloc((size_t)MQ * HH * 2);

  auto cvt = [&](const float* s, unsigned short* d, size_t n) {
    int n4 = (int)(n / 4);
    k_f32_to_bf16<<<dim3((n4 + 255) / 256), 256, 0, stream>>>(s, d, n4);
  };
  cvt(Wih0, Wih0b, (size_t)H3 * II);
  cvt(Whh0, Whh0b, (size_t)H3 * HH);
  cvt(Wih1, Wih1b, (size_t)H3 * HH);
  cvt(Whh1, Whh1b, (size_t)H3 * HH);
  cvt(Wc,   Wcb,   (size_t)HH * 2048);
  cvt(Wv,   Wvb,   (size_t)VV * HH);

  k_embed<<<dim3(BB * SP), 256, 0, stream>>>(input, targets, embed_w, EMBb);
  // zero H1G + H2G + rflag every replay (contiguous: 65536+65536+1536 u32)
  k_zero_u32<<<dim3(518), 256, 0, stream>>>((unsigned int*)H1G, 132608);

  // gi0 = emb @ Wih0^T + bih0   (M=3072, N=3072, K=512), fp32 out
  k_gemm_bt<false, false><<<dim3(24, 24), 256, 0, stream>>>(
      EMBb, Wih0b, bih0, GI0, BB * SP, H3, II);

  // persistent pipelined recurrence (tagged-data, canary+retry poll)
  {
    const unsigned short* a0 = Whh0b; const unsigned short* a1 = Wih1b;
    const unsigned short* a2 = Whh1b; const float* a3 = GI0;
    const float* a4 = bhh0; const float* a5 = bih1; const float* a6 = bhh1;
    unsigned* a7 = H1G; unsigned* a8 = H2G; float* a9 = OBUF;
    unsigned* a10 = CNT;
    void* args[] = {&a0, &a1, &a2, &a3, &a4, &a5, &a6, &a7, &a8, &a9, &a10};
    hipLaunchCooperativeKernel((void*)k_recur, dim3(192), dim3(256),
                               args, 137216u, stream);
  }

  k_attn<<<dim3(128), 256, 0, stream>>>(OBUF, Xb);

  // comb = tanh(X @ Wc^T + bc)  (M=2048, N=1024, K=2048), bf16 out
  k_gemm_bt<true, true><<<dim3(8, 16), 256, 0, stream>>>(
      Xb, Wcb, bc, COMBb, MQ, HH, 2048);

  // logits = comb @ Wv^T + bv   (M=2048, N=32000, K=1024), fp32 -> d_out
  k_gemm_bt<false, false><<<dim3(250, 16), 256, 0, stream>>>(
      COMBb, Wvb, bv, out, MQ, VV, HH);
}

// Round 10
// 4241.323 us; speedup vs baseline: 1.6371x; 1.6371x over previous
//
#include <hip/hip_runtime.h>

// ---------- types / helpers ----------
typedef __attribute__((ext_vector_type(8))) short bf16x8;   // 8 bf16 (4 VGPRs)
typedef __attribute__((ext_vector_type(4))) float f32x4;    // MFMA accumulator

#define GLOAD_LDS16(g, l)                                                     \
  __builtin_amdgcn_global_load_lds(                                           \
      (const __attribute__((address_space(1))) void*)(g),                     \
      (__attribute__((address_space(3))) void*)(l), 16, 0, 0)

#define ALOAD64(p)  __hip_atomic_load((p), __ATOMIC_RELAXED, __HIP_MEMORY_SCOPE_AGENT)
#define ALOADU32(p) __hip_atomic_load((p), __ATOMIC_RELAXED, __HIP_MEMORY_SCOPE_AGENT)
#define ASTOREU32(p, v) __hip_atomic_store((p), (v), __ATOMIC_RELAXED, __HIP_MEMORY_SCOPE_AGENT)

__device__ __forceinline__ unsigned short f2b(float f) {
  union { float f; unsigned int i; } v; v.f = f;
  unsigned int u = v.i;
  u += 0x7fffu + ((u >> 16) & 1u);   // RNE
  return (unsigned short)(u >> 16);
}
__device__ __forceinline__ float sigm(float x) { return 1.f / (1.f + expf(-x)); }

// Problem constants
#define HH   1024
#define H3   3072
#define BB   8
#define SP   384     // padded sequence (383 real + 1 pad)
#define SL   383
#define VV   32000
#define II   512
#define MQ   2048    // B*T rows for attention tail

// TAG(step) = step+1 (flags zeroed in-graph each replay; 0 never matches)
#define TAG(s) ((unsigned)((s) + 1))

// ---------- fp32 -> bf16 bulk convert ----------
__global__ void k_f32_to_bf16(const float* __restrict__ src,
                              unsigned short* __restrict__ dst, int n4) {
  int i = blockIdx.x * 256 + threadIdx.x;
  if (i >= n4) return;
  float4 v = ((const float4*)src)[i];
  ushort4 o;
  o.x = f2b(v.x); o.y = f2b(v.y); o.z = f2b(v.z); o.w = f2b(v.w);
  ((ushort4*)dst)[i] = o;
}

// ---------- zero u32 ----------
__global__ void k_zero_u32(unsigned int* p, int n) {
  int i = blockIdx.x * 256 + threadIdx.x;
  if (i < n) p[i] = 0u;
}

// ---------- embedding gather -> bf16, layout m = b*384 + s ----------
__global__ void k_embed(const int* __restrict__ input, const int* __restrict__ targets,
                        const float* __restrict__ embed_w, unsigned short* __restrict__ emb) {
  int m = blockIdx.x;              // 0..3071
  int b = m / SP, s = m % SP;
  unsigned short* dst = emb + (size_t)m * II;
  if (s == SL) {                   // pad row
    for (int i = threadIdx.x; i < II; i += 256) dst[i] = 0;
    return;
  }
  int tok = (s < 128) ? input[b * 128 + s] : targets[b * 256 + (s - 128)];
  const float* srcw = embed_w + (size_t)tok * II;
  for (int i = threadIdx.x; i < II; i += 256) dst[i] = f2b(srcw[i]);
}

// ---------- 2-phase double-buffered bf16 GEMM: C = A@W^T + bias ----------
template<bool TANH, bool OUTBF16>
__global__ __launch_bounds__(256) void k_gemm_bt(
    const unsigned short* __restrict__ A, const unsigned short* __restrict__ W,
    const float* __restrict__ bias, void* __restrict__ Cout,
    int M, int N, int K) {
  __shared__ __align__(16) unsigned short As[2][128 * 32];
  __shared__ __align__(16) unsigned short Ws[2][128 * 32];
  const int tid = threadIdx.x;
  const int gx = gridDim.x;
  const int nwg = gx * gridDim.y;
  int orig = blockIdx.y * gx + blockIdx.x;
  int wg = ((nwg & 7) == 0) ? ((orig & 7) * (nwg >> 3) + (orig >> 3)) : orig;
  const int mBase = (wg / gx) * 128, nBase = (wg % gx) * 128;
  const int wid = tid >> 6, lane = tid & 63;
  const int wr = wid >> 1, wc = wid & 1;
  f32x4 acc[4][4];
#pragma unroll
  for (int i = 0; i < 4; ++i)
#pragma unroll
    for (int j = 0; j < 4; ++j) acc[i][j] = (f32x4){0.f, 0.f, 0.f, 0.f};

  const int r0 = tid >> 2, c0 = (tid & 3) * 8;   // staging chunk (8 bf16 = 16B)
  const int kq8 = (lane >> 4) * 8;

  auto stage = [&](int kt, int b) {
#pragma unroll
    for (int pass = 0; pass < 2; ++pass) {
      int r = pass * 64 + r0;
      GLOAD_LDS16(A + (size_t)(mBase + r) * K + kt + c0, &As[b][r * 32 + c0]);
      GLOAD_LDS16(W + (size_t)(nBase + r) * K + kt + c0, &Ws[b][r * 32 + c0]);
    }
  };

  stage(0, 0);
  int cur = 0;
  for (int kt = 0; kt < K; kt += 32) {
    asm volatile("s_waitcnt vmcnt(0)" ::: "memory");   // buf[cur] landed
    __syncthreads();
    if (kt + 32 < K) stage(kt + 32, cur ^ 1);          // overlaps with MFMA below
    bf16x8 af[4], bfr[4];
#pragma unroll
    for (int mf = 0; mf < 4; ++mf)
      af[mf] = *(const bf16x8*)&As[cur][(wr * 64 + mf * 16 + (lane & 15)) * 32 + kq8];
#pragma unroll
    for (int nf = 0; nf < 4; ++nf)
      bfr[nf] = *(const bf16x8*)&Ws[cur][(wc * 64 + nf * 16 + (lane & 15)) * 32 + kq8];
#pragma unroll
    for (int mf = 0; mf < 4; ++mf)
#pragma unroll
      for (int nf = 0; nf < 4; ++nf)
        acc[mf][nf] = __builtin_amdgcn_mfma_f32_16x16x32_bf16(af[mf], bfr[nf], acc[mf][nf], 0, 0, 0);
    cur ^= 1;
  }
  const int rq = (lane >> 4) * 4;
#pragma unroll
  for (int mf = 0; mf < 4; ++mf) {
#pragma unroll
    for (int nf = 0; nf < 4; ++nf) {
      int n = nBase + wc * 64 + nf * 16 + (lane & 15);
      float bvv = bias[n];
#pragma unroll
      for (int i = 0; i < 4; ++i) {
        int m = mBase + wr * 64 + mf * 16 + rq + i;
        float v = acc[mf][nf][i] + bvv;
        if (TANH) v = tanhf(v);
        if (OUTBF16) ((unsigned short*)Cout)[(size_t)m * N + n] = f2b(v);
        else         ((float*)Cout)[(size_t)m * N + n] = v;
      }
    }
  }
}

// ---------- persistent cooperative GRU recurrence ----------
// ROUND-7 PROTOCOL VERBATIM (proven): plain bf16 rings (8 slots x 8192),
// pflag1/pflag2 own-word producer flags posted after vmcnt(0)+barrier,
// wave-0 coalesced flag poll, rflag WAR (wave 1, every 4 steps, 4-stale).
// ONLY CHANGE vs r7: B-fragment payload is staged into LDS with COALESCED
// u64 atomic loads (lane-consecutive, 512B/instr; ~9x fewer L3 transactions
// than r7's per-lane 64B-strided 8B loads), unpacked to XOR-swizzled LDS
// (l -> l ^ (b*8), involution shared by write and ds_read), MFMA reads LDS.
__global__ __launch_bounds__(256) void k_recur(
    const unsigned short* __restrict__ whh0, const unsigned short* __restrict__ wih1,
    const unsigned short* __restrict__ whh1,
    const float* __restrict__ gi0,
    const float* __restrict__ bhh0, const float* __restrict__ bih1,
    const float* __restrict__ bhh1,
    unsigned short* __restrict__ h1g, unsigned short* __restrict__ h2g,
    float* __restrict__ Obuf, unsigned* cnt) {
  extern __shared__ unsigned char smem[];
  unsigned short* wlds  = (unsigned short*)smem;              // 48x1024 bf16 = 98304B
  unsigned short* hA    = (unsigned short*)(smem + 98304);    // 8x1024 bf16 = 16384B
  unsigned short* hB    = (unsigned short*)(smem + 114688);   // 16384B
  unsigned short* zrow  = (unsigned short*)(smem + 131072);   // 1024 bf16 zeros
  float*          gacc  = (float*)(smem + 133120);            // 4*16*16 f32 = 4096B

  unsigned* pflag1 = cnt;           // [8][64]
  unsigned* pflag2 = cnt + 512;     // [8][128]
  unsigned* rflag  = cnt + 1536;    // [8][192]

  const int g = blockIdx.x, tid = threadIdx.x;
  const int layer = (g >= 64) ? 1 : 0;
  const int j0 = layer ? (g - 64) * 8 : g * 16;

  // ---- one-time: weight rows into LDS (XOR-swizzled source, linear dest) ----
  for (int p = 0; p < 24; ++p) {
    int c = p * 256 + tid;          // 16B chunks
    int rr = c >> 7;                // LDS row 0..47
    int co = (c & 127) * 8;
    int cs = co ^ ((rr & 7) * 8);
    const unsigned short* src;
    if (layer == 0) {
      int grow = (rr >> 4) * 1024 + j0 + (rr & 15);
      src = whh0 + (size_t)grow * 1024 + cs;
    } else {
      const unsigned short* base; int grow;
      if (rr < 16)      { base = wih1; grow = (rr < 8) ? (j0 + rr) : (1024 + j0 + rr - 8); }
      else if (rr < 32) { base = whh1; int r2 = rr - 16; grow = (r2 < 8) ? (j0 + r2) : (1024 + j0 + r2 - 8); }
      else if (rr < 40) { base = wih1; grow = 2048 + j0 + (rr - 32); }
      else              { base = whh1; grow = 2048 + j0 + (rr - 40); }
      src = base + (size_t)grow * 1024 + cs;
    }
    GLOAD_LDS16(src, wlds + (size_t)rr * 1024 + co);
  }
  { // zero pad row + gacc (zeros feed gates on steps before MFMA starts)
    ((unsigned int*)zrow)[tid]       = 0u;
    ((unsigned int*)zrow)[tid + 256] = 0u;
    for (int i = tid; i < 1024; i += 256) gacc[i] = 0.f;
  }
  __syncthreads();

  const int w = tid >> 6, lane = tid & 63;
  const int arow = lane & 15, kq8 = (lane >> 4) * 8, bb = lane & 15;

  // hoisted gate constants + running state (r7 maps verbatim)
  float c0r = 0.f, c0z = 0.f, c0n = 0.f;
  float c1ir = 0.f, c1iz = 0.f, c1in = 0.f, c1hr = 0.f, c1hz = 0.f, c1hn = 0.f;
  float hprev = 0.f;
  if (layer == 0) {
    if (tid < 128) { int j = j0 + (tid >> 3); c0r = bhh0[j]; c0z = bhh0[1024 + j]; c0n = bhh0[2048 + j]; }
  } else {
    if (tid < 64)  { int j = j0 + (tid >> 3);
      c1ir = bih1[j]; c1iz = bih1[1024 + j]; c1in = bih1[2048 + j];
      c1hr = bhh1[j]; c1hz = bhh1[1024 + j]; c1hn = bhh1[2048 + j]; }
  }

  // MFMA config (constant per thread; r7 structure, B now points into LDS)
  bool wact; int tb, nrows; int hsel;
  if (layer == 0) { wact = (w < 3); tb = w * 16; nrows = 16; hsel = 0; }
  else { wact = true; tb = (w < 2) ? w * 16 : (32 + (w - 2) * 8); nrows = (w < 2) ? 16 : 8;
         hsel = (w & 1); }
  const unsigned short* abase; int ax;
  if (arow < nrows) { abase = wlds + (size_t)(tb + arow) * 1024; ax = (arow & 7) * 8; }
  else              { abase = zrow; ax = 0; }
  const unsigned short* bbase0; int bx;
  {
    const unsigned short* hX = hsel ? hB : hA;
    if (bb < 8) { bbase0 = hX + (size_t)bb * 1024; bx = (bb & 7) * 8; }
    else        { bbase0 = zrow; bx = 0; }
  }
  const int rq = (lane >> 4) * 4;
  const int kbase = w * 512 + lane;   // coalesced staging word base (u64 units)

  for (int s = 0; s < 384; ++s) {
    const bool act = layer ? (s >= 1) : (s <= 382);
    const unsigned short* h1r = h1g + ((s - 1) & 7) * 8192;
    const unsigned short* h2r = h2g + ((s - 2) & 7) * 8192;
    unsigned short* h1w = h1g + (s & 7) * 8192;         // L0 writes h1[s]
    unsigned short* h2w = h2g + ((s - 1) & 7) * 8192;   // L1 writes h2[s-1]

    // 0) gi0 prefetch (L0; normal cached loads; in flight during the poll)
    float pr = 0.f, pz = 0.f, pn = 0.f;
    if (layer == 0 && act && tid < 128) {
      int cc = tid >> 3, b = tid & 7; int j = j0 + cc;
      size_t m3 = ((size_t)b * SP + s) * H3;
      pr = gi0[m3 + j]; pz = gi0[m3 + 1024 + j]; pn = gi0[m3 + 2048 + j];
    }

    // 1) arrival poll (wave 0, coalesced, one word per lane, no RMW) [r7]
    if (w == 0 && act && s >= 1) {
      const unsigned t = TAG(s - 1);
      const bool need2 = (layer == 1) && (s >= 2);
      unsigned* f1 = pflag1 + ((s - 1) & 7) * 64;
      unsigned* f2 = pflag2 + ((s - 1) & 7) * 128;
      for (int it = 0; it < 200000; ++it) {
        int ok = (ALOADU32(f1 + lane) == t);
        if (need2) {
          ok &= (ALOADU32(f2 + lane) == t);
          ok &= (ALOADU32(f2 + 64 + lane) == t);
        }
        if (__all(ok)) break;                 // bounded: loud fail, not a hang
        __builtin_amdgcn_s_sleep(1);
      }
    }
    // WAR check (wave 1, every 4 steps, 4-stale; normally instant) [r7]
    if (w == 1 && (s & 3) == 0 && s >= 4) {
      const unsigned t = TAG(s - 4);
      unsigned* rf = rflag + ((s - 4) & 7) * 192;
      for (int it = 0; it < 100000; ++it) {
        int ok = (ALOADU32(rf + lane) == t)
               & (ALOADU32(rf + 64 + lane) == t)
               & (ALOADU32(rf + 128 + lane) == t);
        if (__all(ok)) break;
        __builtin_amdgcn_s_sleep(1);
      }
    }
    __syncthreads();   // flags confirmed for whole WG before payload reads

    // 2) NEW: coalesced payload staging into LDS (post-flag => no tearing)
    //    slot = [8 batch][1024 col] bf16 = 2048 u64; word k = w*512+i*64+lane;
    //    u64 k = batch k>>8, cols (k&255)*4 .. +3; swizzle l -> l ^ (b*8).
    if (act && s >= 1) {
      const unsigned long long* p1 = (const unsigned long long*)h1r;
#pragma unroll
      for (int i = 0; i < 8; ++i) {
        int k = kbase + i * 64;
        unsigned long long v = ALOAD64(p1 + k);
        int b = k >> 8, e = (k & 255) * 4;
        *(unsigned long long*)(hA + b * 1024 + (e ^ (b * 8))) = v;
      }
      if ((layer == 1) && (s >= 2)) {
        const unsigned long long* p2 = (const unsigned long long*)h2r;
#pragma unroll
        for (int i = 0; i < 8; ++i) {
          int k = kbase + i * 64;
          unsigned long long v = ALOAD64(p2 + k);
          int b = k >> 8, e = (k & 255) * 4;
          *(unsigned long long*)(hB + b * 1024 + (e ^ (b * 8))) = v;
        }
      }
    }
    __syncthreads();   // staged h visible to all waves

    // 3) MFMA from LDS (A: wlds swizzled [r7]; B: hA/hB swizzled [r8 body])
    bool domfma = act && wact && (layer == 0 ? (s >= 1) : (hsel == 0 ? (s >= 1) : (s >= 2)));
    if (domfma) {
      f32x4 a0 = (f32x4){0.f, 0.f, 0.f, 0.f};
      f32x4 a1 = (f32x4){0.f, 0.f, 0.f, 0.f};
#pragma unroll
      for (int kt = 0; kt < 32; kt += 2) {
        int ko0 = kt * 32 + kq8, ko1 = ko0 + 32;
        bf16x8 av0 = *(const bf16x8*)(abase + (ko0 ^ ax));
        bf16x8 hv0 = *(const bf16x8*)(bbase0 + (ko0 ^ bx));
        bf16x8 av1 = *(const bf16x8*)(abase + (ko1 ^ ax));
        bf16x8 hv1 = *(const bf16x8*)(bbase0 + (ko1 ^ bx));
        a0 = __builtin_amdgcn_mfma_f32_16x16x32_bf16(av0, hv0, a0, 0, 0, 0);
        a1 = __builtin_amdgcn_mfma_f32_16x16x32_bf16(av1, hv1, a1, 0, 0, 0);
      }
#pragma unroll
      for (int i = 0; i < 4; ++i)
        gacc[w * 256 + (rq + i) * 16 + (lane & 15)] = a0[i] + a1[i];
    }
    __syncthreads();

    // 4) gates (fp32) + h payload stores (agent 2B atomics) + Obuf [r7]
    if (act) {
      if (layer == 0 && tid < 128) {
        int cc = tid >> 3, b = tid & 7; int j = j0 + cc;
        float gr = pr + gacc[cc * 16 + b]       + c0r;
        float gz = pz + gacc[256 + cc * 16 + b] + c0z;
        float hg =      gacc[512 + cc * 16 + b] + c0n;
        float r = sigm(gr), z = sigm(gz);
        float n = tanhf(pn + r * hg);
        float hn = (1.f - z) * n + z * hprev;
        hprev = hn;
        __hip_atomic_store(h1w + b * 1024 + j, f2b(hn),
                           __ATOMIC_RELAXED, __HIP_MEMORY_SCOPE_AGENT);
      } else if (layer == 1 && tid < 64) {
        int cc = tid >> 3, b = tid & 7; int j = j0 + cc;
        float gr = gacc[cc * 16 + b]       + c1ir + gacc[256 + cc * 16 + b]       + c1hr;
        float gz = gacc[(8 + cc) * 16 + b] + c1iz + gacc[256 + (8 + cc) * 16 + b] + c1hz;
        float gn = gacc[512 + cc * 16 + b] + c1in;
        float hg = gacc[768 + cc * 16 + b] + c1hn;
        float r = sigm(gr), z = sigm(gz);
        float n = tanhf(gn + r * hg);
        float hn = (1.f - z) * n + z * hprev;
        hprev = hn;
        __hip_atomic_store(h2w + b * 1024 + j, f2b(hn),
                           __ATOMIC_RELAXED, __HIP_MEMORY_SCOPE_AGENT);
        Obuf[((size_t)b * SP + (s - 1)) * 1024 + j] = hn;
      }
    }
    // 5) release: stores acked (vmcnt0 + barrier) -> post own flags [r7]
    asm volatile("s_waitcnt vmcnt(0)" ::: "memory");
    __syncthreads();
    if (act && tid == 0) {
      if (layer == 0) ASTOREU32(pflag1 + (s & 7) * 64 + g, TAG(s));
      else            ASTOREU32(pflag2 + (s & 7) * 128 + (g - 64), TAG(s));
    }
    if (tid == 1) ASTOREU32(rflag + (s & 7) * 192 + g, TAG(s));
  }
}

// ---------- fused masked attention (fp32), writes X = [Q | ctx] as bf16 ----------
__global__ __launch_bounds__(256) void k_attn(const float* __restrict__ O,
                                              unsigned short* __restrict__ X) {
  __shared__ float sc[16][384];
  __shared__ float red[16][16];
  __shared__ float rowstat[16];
  const int wg = blockIdx.x;
  const int b = wg >> 4, q0 = (wg & 15) * 16;
  const int tid = threadIdx.x;
  const int qi = tid >> 4, kk = tid & 15;
  const int q = q0 + qi;                       // 0..255
  const float* Ob = O + (size_t)b * SP * 1024;
  const float* Qrow = Ob + (size_t)(127 + q) * 1024;

  for (int kb = 0; kb < 24; ++kb) {
    int k = kb * 16 + kk;
    float v = -INFINITY;
    if (k < 127 + q) {
      const float* Orow = Ob + (size_t)k * 1024;
      float a = 0.f;
      for (int h = 0; h < 1024; h += 4) {
        float4 qv = *(const float4*)(Qrow + h);
        float4 ov = *(const float4*)(Orow + h);
        a += qv.x * ov.x + qv.y * ov.y + qv.z * ov.z + qv.w * ov.w;
      }
      v = a;
    }
    sc[qi][k] = v;
  }
  __syncthreads();
  float mx = -INFINITY;
  for (int k = kk; k < 384; k += 16) mx = fmaxf(mx, sc[qi][k]);
  red[qi][kk] = mx;
  __syncthreads();
  if (kk == 0) {
    float m2 = -INFINITY;
    for (int i = 0; i < 16; ++i) m2 = fmaxf(m2, red[qi][i]);
    rowstat[qi] = m2;
  }
  __syncthreads();
  float rmax = rowstat[qi];
  float lsum = 0.f;
  for (int k = kk; k < 384; k += 16) {
    float v = sc[qi][k];
    float e = (v == -INFINITY) ? 0.f : expf(v - rmax);
    sc[qi][k] = e; lsum += e;
  }
  red[qi][kk] = lsum;
  __syncthreads();
  if (kk == 0) {
    float s2 = 0.f;
    for (int i = 0; i < 16; ++i) s2 += red[qi][i];
    rowstat[qi] = 1.f / s2;
  }
  __syncthreads();
  float rinv = rowstat[qi];

  const int hb = kk * 64;
  float4 acc[16];
#pragma unroll
  for (int i = 0; i < 16; ++i) acc[i] = (float4){0.f, 0.f, 0.f, 0.f};
  for (int k = 0; k < 127 + q; ++k) {
    float a = sc[qi][k];
    const float* Orow = Ob + (size_t)k * 1024 + hb;
#pragma unroll
    for (int i = 0; i < 16; ++i) {
      float4 ov = *(const float4*)(Orow + i * 4);
      acc[i].x += a * ov.x; acc[i].y += a * ov.y;
      acc[i].z += a * ov.z; acc[i].w += a * ov.w;
    }
  }
  unsigned short* Xrow = X + (size_t)(b * 256 + q) * 2048;
#pragma unroll
  for (int i = 0; i < 16; ++i) {
    int h = hb + i * 4;
    float4 qv = *(const float4*)(Qrow + h);
    Xrow[h + 0] = f2b(qv.x); Xrow[h + 1] = f2b(qv.y);
    Xrow[h + 2] = f2b(qv.z); Xrow[h + 3] = f2b(qv.w);
    Xrow[1024 + h + 0] = f2b(acc[i].x * rinv);
    Xrow[1024 + h + 1] = f2b(acc[i].y * rinv);
    Xrow[1024 + h + 2] = f2b(acc[i].z * rinv);
    Xrow[1024 + h + 3] = f2b(acc[i].w * rinv);
  }
}

// ---------- host ----------
extern "C" void kernel_launch(void* const* d_in, const int* in_sizes, int n_in,
                              void* d_out, int out_size, void* d_ws, size_t ws_size,
                              hipStream_t stream) {
  (void)in_sizes; (void)n_in; (void)out_size; (void)ws_size;
  const int*   input   = (const int*)d_in[0];
  const int*   targets = (const int*)d_in[1];
  const float* embed_w = (const float*)d_in[2];
  const float* Wih0 = (const float*)d_in[3];
  const float* Whh0 = (const float*)d_in[4];
  const float* bih0 = (const float*)d_in[5];
  const float* bhh0 = (const float*)d_in[6];
  const float* Wih1 = (const float*)d_in[7];
  const float* Whh1 = (const float*)d_in[8];
  const float* bih1 = (const float*)d_in[9];
  const float* bhh1 = (const float*)d_in[10];
  const float* Wc   = (const float*)d_in[11];
  const float* bc   = (const float*)d_in[12];
  const float* Wv   = (const float*)d_in[13];
  const float* bv   = (const float*)d_in[14];
  float* out = (float*)d_out;

  char* ws = (char*)d_ws;
  size_t off = 0;
  auto alloc = [&](size_t bytes) {
    void* p = ws + off; off += (bytes + 255) & ~(size_t)255; return p;
  };
  unsigned short* Wih0b = (unsigned short*)alloc((size_t)H3 * II * 2);
  unsigned short* Whh0b = (unsigned short*)alloc((size_t)H3 * HH * 2);
  unsigned short* Wih1b = (unsigned short*)alloc((size_t)H3 * HH * 2);
  unsigned short* Whh1b = (unsigned short*)alloc((size_t)H3 * HH * 2);
  unsigned short* Wcb   = (unsigned short*)alloc((size_t)HH * 2048 * 2);
  unsigned short* Wvb   = (unsigned short*)alloc((size_t)VV * HH * 2);
  unsigned short* EMBb  = (unsigned short*)alloc((size_t)BB * SP * II * 2);
  float*          GI0   = (float*)alloc((size_t)BB * SP * H3 * 4);
  unsigned short* H1G   = (unsigned short*)alloc(8 * 8192 * 2);   // 128KB ring
  unsigned short* H2G   = (unsigned short*)alloc(8 * 8192 * 2);   // 128KB ring
  unsigned*       CNT   = (unsigned*)alloc(3072 * 4);             // pflag1/2 + rflag
  float*          OBUF  = (float*)alloc((size_t)BB * SP * HH * 4);
  unsigned short* Xb    = (unsigned short*)alloc((size_t)MQ * 2048 * 2);
  unsigned short* COMBb = (unsigned short*)alloc((size_t)MQ * HH * 2);

  auto cvt = [&](const float* s, unsigned short* d, size_t n) {
    int n4 = (int)(n / 4);
    k_f32_to_bf16<<<dim3((n4 + 255) / 256), 256, 0, stream>>>(s, d, n4);
  };
  cvt(Wih0, Wih0b, (size_t)H3 * II);
  cvt(Whh0, Whh0b, (size_t)H3 * HH);
  cvt(Wih1, Wih1b, (size_t)H3 * HH);
  cvt(Whh1, Whh1b, (size_t)H3 * HH);
  cvt(Wc,   Wcb,   (size_t)HH * 2048);
  cvt(Wv,   Wvb,   (size_t)VV * HH);

  k_embed<<<dim3(BB * SP), 256, 0, stream>>>(input, targets, embed_w, EMBb);
  k_zero_u32<<<dim3(12), 256, 0, stream>>>((unsigned int*)CNT, 3072);

  // gi0 = emb @ Wih0^T + bih0   (M=3072, N=3072, K=512), fp32 out
  k_gemm_bt<false, false><<<dim3(24, 24), 256, 0, stream>>>(
      EMBb, Wih0b, bih0, GI0, BB * SP, H3, II);

  // persistent pipelined recurrence (r7 protocol + coalesced LDS staging)
  {
    const unsigned short* a0 = Whh0b; const unsigned short* a1 = Wih1b;
    const unsigned short* a2 = Whh1b; const float* a3 = GI0;
    const float* a4 = bhh0; const float* a5 = bih1; const float* a6 = bhh1;
    unsigned short* a7 = H1G; unsigned short* a8 = H2G; float* a9 = OBUF;
    unsigned* a10 = CNT;
    void* args[] = {&a0, &a1, &a2, &a3, &a4, &a5, &a6, &a7, &a8, &a9, &a10};
    hipLaunchCooperativeKernel((void*)k_recur, dim3(192), dim3(256),
                               args, 137216u, stream);
  }

  k_attn<<<dim3(128), 256, 0, stream>>>(OBUF, Xb);

  // comb = tanh(X @ Wc^T + bc)  (M=2048, N=1024, K=2048), bf16 out
  k_gemm_bt<true, true><<<dim3(8, 16), 256, 0, stream>>>(
      Xb, Wcb, bc, COMBb, MQ, HH, 2048);

  // logits = comb @ Wv^T + bv   (M=2048, N=32000, K=1024), fp32 -> d_out
  k_gemm_bt<false, false><<<dim3(250, 16), 256, 0, stream>>>(
      COMBb, Wvb, bv, out, MQ, VV, HH);
}